// Round 9
// baseline (417.277 us; speedup 1.0000x reference)
//
#include <hip/hip_runtime.h>
#include <hip/hip_bf16.h>
#include <math.h>

#define LEAK 0.2f

typedef __attribute__((ext_vector_type(8))) short bf16x8;
typedef __attribute__((ext_vector_type(4))) float f32x4;

__device__ __forceinline__ float leaky(float v) { return v > 0.f ? v : LEAK * v; }

__device__ __forceinline__ unsigned short bf16rne(float f) {
  unsigned int u = __float_as_uint(f);
  u = (u + 0x7FFFu + ((u >> 16) & 1u)) >> 16;
  return (unsigned short)u;
}

__device__ __forceinline__ float bf2f(unsigned short v) {
  return __uint_as_float((unsigned int)v << 16);
}

__device__ __forceinline__ unsigned int pack2(float lo, float hi) {
  unsigned int a = __float_as_uint(lo);
  unsigned int b = __float_as_uint(hi);
  a = (a + 0x7FFFu + ((a >> 16) & 1u)) >> 16;
  b = (b + 0x7FFFu + ((b >> 16) & 1u)) >> 16;
  return (b << 16) | (a & 0xFFFFu);
}

// fp32x8 -> bf16x8 via packed cvt
__device__ __forceinline__ bf16x8 pack8(const float4 a, const float4 b) {
  union { __hip_bfloat162 h[4]; bf16x8 v; } r;
  r.h[0] = __float22bfloat162_rn(make_float2(a.x, a.y));
  r.h[1] = __float22bfloat162_rn(make_float2(a.z, a.w));
  r.h[2] = __float22bfloat162_rn(make_float2(b.x, b.y));
  r.h[3] = __float22bfloat162_rn(make_float2(b.z, b.w));
  return r.v;
}

__device__ __forceinline__ void load_edge(const void* ei, int mode, int e, int E,
                                          int& s, int& d) {
  if (mode) {
    const long long* p = (const long long*)ei;
    s = (int)p[e];
    d = (int)p[(size_t)E + e];
  } else {
    const int* p = (const int*)ei;
    s = p[e];
    d = p[(size_t)E + e];
  }
}

// setup: W1/W2 transpose+bf16, edge dtype detect, deg zero — one launch
__global__ __launch_bounds__(256) void setup_k(const float* __restrict__ W1,
                                               const float* __restrict__ W2,
                                               const int* __restrict__ ei,
                                               unsigned short* __restrict__ Wt,
                                               unsigned short* __restrict__ Wt2,
                                               int* flag, int* deg, int N) {
  const int b = blockIdx.x, t = threadIdx.x;
  if (b < 128) {
    int idx = b * 256 + t;
    int j = idx & 63, k = idx >> 6;
    Wt[j * 512 + k] = bf16rne(W1[k * 64 + j]);
  } else if (b < 144) {
    int idx = (b - 128) * 256 + t;
    int j = idx & 63, k = idx >> 6;
    Wt2[j * 64 + k] = bf16rne(W2[k * 64 + j]);
  } else if (b == 144) {
    if (t == 0) {
      int allzero = 1;
      for (int k = 0; k < 64; ++k)
        if (ei[2 * k + 1] != 0) { allzero = 0; break; }
      *flag = allzero;
    }
  } else {
    int i = (b - 145) * 256 + t;
    if (i <= N) deg[i] = 0;
  }
}

// one-time edge compaction to int32 (incl. self-loops)
__global__ __launch_bounds__(256) void conv_k(const void* ei, const int* flag,
                                              int* __restrict__ src32,
                                              int* __restrict__ dst32,
                                              int E, int Et) {
  int e = blockIdx.x * 256 + threadIdx.x;
  if (e >= Et) return;
  int mode = *flag;
  int s, d;
  if (e < E) load_edge(ei, mode, e, E, s, d);
  else { s = e - E; d = s; }
  src32[e] = s;
  dst32[e] = d;
}

// XCD-partitioned histogram over compact dst32
__global__ __launch_bounds__(256) void histx_k(const int* __restrict__ dst32,
                                               int* deg, int Et, int N) {
  const int xcd = blockIdx.x & 7;
  const int grp = blockIdx.x >> 3;
  const int ngrp = gridDim.x >> 3;
  const int R = (N + 7) >> 3;
  const int lo = xcd * R;
  const int hi = min(lo + R, N);
  const int per = (Et + ngrp - 1) / ngrp;
  const int e0 = grp * per;
  const int e1 = min(e0 + per, Et);
  for (int e = e0 + (int)threadIdx.x; e < e1; e += 256) {
    int d = dst32[e];
    if (d >= lo && d < hi) atomicAdd(&deg[d], 1);
  }
}

__global__ __launch_bounds__(256) void psum_k(const int* __restrict__ deg,
                                              int* __restrict__ bsum, int N) {
  int i = blockIdx.x * 256 + threadIdx.x;
  int v = (i < N) ? deg[i] : 0;
#pragma unroll
  for (int o = 32; o; o >>= 1) v += __shfl_xor(v, o, 64);
  __shared__ int wsum[4];
  if ((threadIdx.x & 63) == 0) wsum[threadIdx.x >> 6] = v;
  __syncthreads();
  if (threadIdx.x == 0) bsum[blockIdx.x] = wsum[0] + wsum[1] + wsum[2] + wsum[3];
}

__global__ __launch_bounds__(1024) void bscan_k(const int* __restrict__ bsum,
                                                int* __restrict__ boff, int nb) {
  __shared__ int s[1024];
  int t = threadIdx.x;
  s[t] = (t < nb) ? bsum[t] : 0;
  __syncthreads();
  for (int off = 1; off < 1024; off <<= 1) {
    int v = (t >= off) ? s[t - off] : 0;
    __syncthreads();
    s[t] += v;
    __syncthreads();
  }
  if (t < nb) boff[t] = (t == 0) ? 0 : s[t - 1];
}

__global__ __launch_bounds__(256) void escan_k(const int* __restrict__ deg,
                                               const int* __restrict__ boff,
                                               int* __restrict__ start,
                                               int* __restrict__ cursor,
                                               int N, int Et) {
  int i = blockIdx.x * 256 + threadIdx.x;
  int t = threadIdx.x;
  int v = (i < N) ? deg[i] : 0;
  __shared__ int s[256];
  s[t] = v;
  __syncthreads();
  for (int off = 1; off < 256; off <<= 1) {
    int u = (t >= off) ? s[t - off] : 0;
    __syncthreads();
    s[t] += u;
    __syncthreads();
  }
  if (i < N) {
    int pos = boff[blockIdx.x] + s[t] - v;
    start[i] = pos;
    cursor[i] = pos;
  }
  if (i == 0) start[N] = Et;
}

// XCD-partitioned CSR fill over compact arrays
__global__ __launch_bounds__(256) void fillx_k(const int* __restrict__ src32,
                                               const int* __restrict__ dst32,
                                               int* cursor, int* __restrict__ csr,
                                               int Et, int N) {
  const int xcd = blockIdx.x & 7;
  const int grp = blockIdx.x >> 3;
  const int ngrp = gridDim.x >> 3;
  const int R = (N + 7) >> 3;
  const int lo = xcd * R;
  const int hi = min(lo + R, N);
  const int per = (Et + ngrp - 1) / ngrp;
  const int e0 = grp * per;
  const int e1 = min(e0 + per, Et);
  for (int e = e0 + (int)threadIdx.x; e < e1; e += 256) {
    int d = dst32[e];
    if (d >= lo && d < hi) {
      int pos = atomicAdd(&cursor[d], 1);
      csr[pos] = src32[e];
    }
  }
}

// xl1 = x@W1 via bf16 MFMA (no LDS) + fused attn1 dots
__global__ __launch_bounds__(256) void gemm1_mfma(const float* __restrict__ x,
                                                  const unsigned short* __restrict__ Wt,
                                                  const float* __restrict__ attS1,
                                                  const float* __restrict__ attD1,
                                                  unsigned short* __restrict__ xlh,
                                                  float* __restrict__ a_src,
                                                  float* __restrict__ a_dst, int N) {
  const int t = threadIdx.x;
  const int w = t >> 6, lane = t & 63;
  const int row0 = blockIdx.x * 64;
  int arow = row0 + w * 16 + (lane & 15);
  if (arow > N - 1) arow = N - 1;
  const int koff = (lane >> 4) * 8;
  const int bcol = lane & 15;
  const int bk = (lane >> 4) * 8;
  const float* xrow = x + (size_t)arow * 512 + koff;

  f32x4 acc[4] = {f32x4{0.f, 0.f, 0.f, 0.f}, f32x4{0.f, 0.f, 0.f, 0.f},
                  f32x4{0.f, 0.f, 0.f, 0.f}, f32x4{0.f, 0.f, 0.f, 0.f}};
#pragma unroll 4
  for (int ks = 0; ks < 16; ++ks) {
    const float4* g = (const float4*)(xrow + ks * 32);
    bf16x8 afrag = pack8(g[0], g[1]);
#pragma unroll
    for (int nt = 0; nt < 4; ++nt) {
      bf16x8 bfrag = *(const bf16x8*)(Wt + (nt * 16 + bcol) * 512 + ks * 32 + bk);
      acc[nt] = __builtin_amdgcn_mfma_f32_16x16x32_bf16(afrag, bfrag, acc[nt], 0, 0, 0);
    }
  }
  const int orow = row0 + w * 16 + (lane >> 4) * 4;
#pragma unroll
  for (int nt = 0; nt < 4; ++nt)
#pragma unroll
    for (int r = 0; r < 4; ++r) {
      int rr = orow + r;
      if (rr < N) xlh[(size_t)rr * 64 + nt * 16 + bcol] = bf16rne(acc[nt][r]);
    }
  float aS[4], aD[4];
#pragma unroll
  for (int nt = 0; nt < 4; ++nt) {
    aS[nt] = attS1[nt * 16 + bcol];
    aD[nt] = attD1[nt * 16 + bcol];
  }
#pragma unroll
  for (int r = 0; r < 4; ++r) {
    int rr = orow + r;
#pragma unroll
    for (int nt = 0; nt < 4; ++nt) {
      float vS = acc[nt][r] * aS[nt];
      float vD = acc[nt][r] * aD[nt];
      vS += __shfl_xor(vS, 1, 64);
      vD += __shfl_xor(vD, 1, 64);
      vS += __shfl_xor(vS, 2, 64);
      vD += __shfl_xor(vD, 2, 64);
      vS += __shfl_xor(vS, 4, 64);
      vD += __shfl_xor(vD, 4, 64);
      if ((bcol & 7) == 0 && rr < N) {
        int head = nt * 2 + (bcol >> 3);
        a_src[rr * 8 + head] = vS;
        a_dst[rr * 8 + head] = vD;
      }
    }
  }
}

// FUSED layer-1 gather + ELU + h@W2 (in-wave matvec) + attn2 dots.
// One wave per node. After the gather butterfly every lane holds the full
// per-cg h slice, so gemm2 is 8 Wt2 loads + 64 readlane-FMAs per node.
__global__ __launch_bounds__(256) void l15_k(const int* __restrict__ start,
                                             const int* __restrict__ csr,
                                             const float* __restrict__ asrc,
                                             const float* __restrict__ adst,
                                             const unsigned short* __restrict__ xlh,
                                             const float* __restrict__ b1,
                                             const unsigned short* __restrict__ Wt2,
                                             const float* __restrict__ attS2,
                                             const float* __restrict__ attD2,
                                             unsigned short* __restrict__ xl2h,
                                             float* __restrict__ a2s,
                                             float* __restrict__ a2d, int N) {
  int g = blockIdx.x * 256 + threadIdx.x;
  int n = g >> 6;
  if (n >= N) return;
  const int lane = threadIdx.x & 63;
  const int es = lane >> 3, cg = lane & 7;
  const int s0 = start[n];
  const int deg = start[n + 1] - s0;
  const float adn = adst[n * 8 + cg];

  float acc[8] = {0.f, 0.f, 0.f, 0.f, 0.f, 0.f, 0.f, 0.f};
  float dsum = 0.f;

  for (int base = 0; base < deg; base += 64) {
    int rem = deg - base;
    if (rem > 64) rem = 64;
    int sreg = (lane < rem) ? csr[s0 + base + lane] : 0;
    for (int jb = 0; jb * 8 < rem; ++jb) {
      const int idx = jb * 8 + es;
      const int s = __shfl(sreg, idx, 64);
      const bool valid = idx < rem;
      float ev = leaky(asrc[s * 8 + cg] + adn);
      float w = valid ? __expf(ev) : 0.f;
      dsum += w;
      const uint4 row = *(const uint4*)(xlh + (size_t)s * 64 + cg * 8);
      acc[0] = fmaf(w, __uint_as_float(row.x << 16), acc[0]);
      acc[1] = fmaf(w, __uint_as_float(row.x & 0xffff0000u), acc[1]);
      acc[2] = fmaf(w, __uint_as_float(row.y << 16), acc[2]);
      acc[3] = fmaf(w, __uint_as_float(row.y & 0xffff0000u), acc[3]);
      acc[4] = fmaf(w, __uint_as_float(row.z << 16), acc[4]);
      acc[5] = fmaf(w, __uint_as_float(row.z & 0xffff0000u), acc[5]);
      acc[6] = fmaf(w, __uint_as_float(row.w << 16), acc[6]);
      acc[7] = fmaf(w, __uint_as_float(row.w & 0xffff0000u), acc[7]);
    }
  }
#pragma unroll
  for (int o = 8; o < 64; o <<= 1) {
    dsum += __shfl_xor(dsum, o, 64);
#pragma unroll
    for (int c = 0; c < 8; ++c) acc[c] += __shfl_xor(acc[c], o, 64);
  }
  // ELU + bias in all lanes: lane (es,cg) holds h[n][cg*8+c]
  const float inv = 1.f / fmaxf(dsum, 1e-16f);
  float v0 = acc[0] * inv + b1[cg * 8 + 0];
  float v1 = acc[1] * inv + b1[cg * 8 + 1];
  float v2 = acc[2] * inv + b1[cg * 8 + 2];
  float v3 = acc[3] * inv + b1[cg * 8 + 3];
  float v4 = acc[4] * inv + b1[cg * 8 + 4];
  float v5 = acc[5] * inv + b1[cg * 8 + 5];
  float v6 = acc[6] * inv + b1[cg * 8 + 6];
  float v7 = acc[7] * inv + b1[cg * 8 + 7];
  v0 = v0 > 0.f ? v0 : __expf(v0) - 1.f;
  v1 = v1 > 0.f ? v1 : __expf(v1) - 1.f;
  v2 = v2 > 0.f ? v2 : __expf(v2) - 1.f;
  v3 = v3 > 0.f ? v3 : __expf(v3) - 1.f;
  v4 = v4 > 0.f ? v4 : __expf(v4) - 1.f;
  v5 = v5 > 0.f ? v5 : __expf(v5) - 1.f;
  v6 = v6 > 0.f ? v6 : __expf(v6) - 1.f;
  v7 = v7 > 0.f ? v7 : __expf(v7) - 1.f;
  // in-wave gemm2: out[j=lane] = sum_k h[k] * W2[k][j]; h[cgk*8+c] from lane cgk
  float o2 = 0.f;
#pragma unroll
  for (int cgk = 0; cgk < 8; ++cgk) {
    bf16x8 wrow = *(const bf16x8*)(Wt2 + lane * 64 + cgk * 8);
    o2 = fmaf(__shfl(v0, cgk, 64), bf2f((unsigned short)wrow[0]), o2);
    o2 = fmaf(__shfl(v1, cgk, 64), bf2f((unsigned short)wrow[1]), o2);
    o2 = fmaf(__shfl(v2, cgk, 64), bf2f((unsigned short)wrow[2]), o2);
    o2 = fmaf(__shfl(v3, cgk, 64), bf2f((unsigned short)wrow[3]), o2);
    o2 = fmaf(__shfl(v4, cgk, 64), bf2f((unsigned short)wrow[4]), o2);
    o2 = fmaf(__shfl(v5, cgk, 64), bf2f((unsigned short)wrow[5]), o2);
    o2 = fmaf(__shfl(v6, cgk, 64), bf2f((unsigned short)wrow[6]), o2);
    o2 = fmaf(__shfl(v7, cgk, 64), bf2f((unsigned short)wrow[7]), o2);
  }
  // attn2 dots + write
  float vS = o2 * attS2[lane];
  float vD = o2 * attD2[lane];
#pragma unroll
  for (int o = 32; o; o >>= 1) {
    vS += __shfl_xor(vS, o, 64);
    vD += __shfl_xor(vD, o, 64);
  }
  if (lane == 0) {
    a2s[n] = vS;
    a2d[n] = vD;
  }
  xl2h[(size_t)n * 64 + lane] = bf16rne(o2);
}

// layer-2 gather + bias + log_softmax, (es,cg) structure
__global__ __launch_bounds__(256) void gather2(const int* __restrict__ start,
                                               const int* __restrict__ csr,
                                               const float* __restrict__ a2s,
                                               const float* __restrict__ a2d,
                                               const unsigned short* __restrict__ xl2h,
                                               const float* __restrict__ b2,
                                               float* __restrict__ out, int N) {
  int g = blockIdx.x * 256 + threadIdx.x;
  int n = g >> 6;
  if (n >= N) return;
  const int lane = threadIdx.x & 63;
  const int es = lane >> 3, cg = lane & 7;
  const int s0 = start[n];
  const int deg = start[n + 1] - s0;
  const float adn = a2d[n];

  float acc[8] = {0.f, 0.f, 0.f, 0.f, 0.f, 0.f, 0.f, 0.f};
  float dsum = 0.f;

  for (int base = 0; base < deg; base += 64) {
    int rem = deg - base;
    if (rem > 64) rem = 64;
    int sreg = (lane < rem) ? csr[s0 + base + lane] : 0;
    for (int jb = 0; jb * 8 < rem; ++jb) {
      const int idx = jb * 8 + es;
      const int s = __shfl(sreg, idx, 64);
      const bool valid = idx < rem;
      float ev = leaky(a2s[s] + adn);
      float w = valid ? __expf(ev) : 0.f;
      dsum += w;
      const uint4 row = *(const uint4*)(xl2h + (size_t)s * 64 + cg * 8);
      acc[0] = fmaf(w, __uint_as_float(row.x << 16), acc[0]);
      acc[1] = fmaf(w, __uint_as_float(row.x & 0xffff0000u), acc[1]);
      acc[2] = fmaf(w, __uint_as_float(row.y << 16), acc[2]);
      acc[3] = fmaf(w, __uint_as_float(row.y & 0xffff0000u), acc[3]);
      acc[4] = fmaf(w, __uint_as_float(row.z << 16), acc[4]);
      acc[5] = fmaf(w, __uint_as_float(row.z & 0xffff0000u), acc[5]);
      acc[6] = fmaf(w, __uint_as_float(row.w << 16), acc[6]);
      acc[7] = fmaf(w, __uint_as_float(row.w & 0xffff0000u), acc[7]);
    }
  }
#pragma unroll
  for (int o = 8; o < 64; o <<= 1) {
    dsum += __shfl_xor(dsum, o, 64);
#pragma unroll
    for (int c = 0; c < 8; ++c) acc[c] += __shfl_xor(acc[c], o, 64);
  }
  const float inv = 1.f / fmaxf(dsum, 1e-16f);
  float v[8];
  float mm = -INFINITY;
#pragma unroll
  for (int c = 0; c < 8; ++c) {
    v[c] = acc[c] * inv + b2[cg * 8 + c];
    mm = fmaxf(mm, v[c]);
  }
  mm = fmaxf(mm, __shfl_xor(mm, 1, 64));
  mm = fmaxf(mm, __shfl_xor(mm, 2, 64));
  mm = fmaxf(mm, __shfl_xor(mm, 4, 64));
  float ss = 0.f;
#pragma unroll
  for (int c = 0; c < 8; ++c) ss += __expf(v[c] - mm);
  ss += __shfl_xor(ss, 1, 64);
  ss += __shfl_xor(ss, 2, 64);
  ss += __shfl_xor(ss, 4, 64);
  const float lg = mm + logf(ss);
  if (es == 0) {
    float4 o0 = {v[0] - lg, v[1] - lg, v[2] - lg, v[3] - lg};
    float4 o1 = {v[4] - lg, v[5] - lg, v[6] - lg, v[7] - lg};
    float4* op = (float4*)(out + (size_t)n * 64 + cg * 8);
    op[0] = o0;
    op[1] = o1;
  }
}

extern "C" void kernel_launch(void* const* d_in, const int* in_sizes, int n_in,
                              void* d_out, int out_size, void* d_ws, size_t ws_size,
                              hipStream_t stream) {
  const float* x = (const float*)d_in[0];
  const void* ei = d_in[1];
  const float* W1 = (const float*)d_in[2];
  const float* att_src1 = (const float*)d_in[3];
  const float* att_dst1 = (const float*)d_in[4];
  const float* b1 = (const float*)d_in[5];
  const float* W2 = (const float*)d_in[6];
  const float* att_src2 = (const float*)d_in[7];
  const float* att_dst2 = (const float*)d_in[8];
  const float* b2 = (const float*)d_in[9];
  float* out = (float*)d_out;

  const int N = in_sizes[0] / 512;
  const int E = in_sizes[1] / 2;
  const int Et = E + N;
  const int nb = (N + 255) / 256;
  const int nz = (N + 1 + 255) / 256;

  float* ws = (float*)d_ws;
  size_t o = 0;
  unsigned short* xlh = (unsigned short*)(ws + o); o += (size_t)N * 32;
  unsigned short* xl2h = (unsigned short*)(ws + o); o += (size_t)N * 32;
  unsigned short* Wt = (unsigned short*)(ws + o); o += 16384;
  unsigned short* Wt2 = (unsigned short*)(ws + o); o += 2048;
  float* asrc1 = ws + o; o += (size_t)N * 8;
  float* adst1 = ws + o; o += (size_t)N * 8;
  float* a2s = ws + o; o += (size_t)N;
  float* a2d = ws + o; o += (size_t)N;
  int* deg = (int*)(ws + o); o += (size_t)N + 1;
  int* start = (int*)(ws + o); o += (size_t)N + 1;
  int* cursor = (int*)(ws + o); o += (size_t)N + 1;
  int* csr = (int*)(ws + o); o += (size_t)Et;
  int* src32 = (int*)(ws + o); o += (size_t)Et;
  int* dst32 = (int*)(ws + o); o += (size_t)Et;
  int* flag = (int*)(ws + o); o += 1;
  int* bsum = (int*)(ws + o); o += (size_t)nb;
  int* boff = (int*)(ws + o); o += (size_t)nb;

  setup_k<<<145 + nz, 256, 0, stream>>>(W1, W2, (const int*)ei, Wt, Wt2, flag, deg, N);
  conv_k<<<(Et + 255) / 256, 256, 0, stream>>>(ei, flag, src32, dst32, E, Et);
  // CSR build (XCD-partitioned hist/fill over compact int32)
  histx_k<<<2048, 256, 0, stream>>>(dst32, deg, Et, N);
  psum_k<<<nb, 256, 0, stream>>>(deg, bsum, N);
  bscan_k<<<1, 1024, 0, stream>>>(bsum, boff, nb);
  escan_k<<<nb, 256, 0, stream>>>(deg, boff, start, cursor, N, Et);
  fillx_k<<<2048, 256, 0, stream>>>(src32, dst32, cursor, csr, Et, N);
  // layer 1
  gemm1_mfma<<<(N + 63) / 64, 256, 0, stream>>>(x, Wt, att_src1, att_dst1, xlh,
                                                asrc1, adst1, N);
  // fused gather1 + ELU + gemm2 + attn2
  l15_k<<<(N * 64 + 255) / 256, 256, 0, stream>>>(start, csr, asrc1, adst1, xlh,
                                                  b1, Wt2, att_src2, att_dst2,
                                                  xl2h, a2s, a2d, N);
  // layer 2 gather + log_softmax
  gather2<<<(N * 64 + 255) / 256, 256, 0, stream>>>(start, csr, a2s, a2d, xl2h,
                                                    b2, out, N);
}

// Round 10
// 370.617 us; speedup vs baseline: 1.1259x; 1.1259x over previous
//
#include <hip/hip_runtime.h>
#include <hip/hip_bf16.h>
#include <math.h>

#define LEAK 0.2f

typedef __attribute__((ext_vector_type(8))) short bf16x8;
typedef __attribute__((ext_vector_type(4))) float f32x4;

__device__ __forceinline__ float leaky(float v) { return v > 0.f ? v : LEAK * v; }

__device__ __forceinline__ unsigned short bf16rne(float f) {
  unsigned int u = __float_as_uint(f);
  u = (u + 0x7FFFu + ((u >> 16) & 1u)) >> 16;
  return (unsigned short)u;
}

__device__ __forceinline__ float bf2f(unsigned short v) {
  return __uint_as_float((unsigned int)v << 16);
}

__device__ __forceinline__ unsigned int pack2(float lo, float hi) {
  unsigned int a = __float_as_uint(lo);
  unsigned int b = __float_as_uint(hi);
  a = (a + 0x7FFFu + ((a >> 16) & 1u)) >> 16;
  b = (b + 0x7FFFu + ((b >> 16) & 1u)) >> 16;
  return (b << 16) | (a & 0xFFFFu);
}

// fp32x8 -> bf16x8 via packed cvt
__device__ __forceinline__ bf16x8 pack8(const float4 a, const float4 b) {
  union { __hip_bfloat162 h[4]; bf16x8 v; } r;
  r.h[0] = __float22bfloat162_rn(make_float2(a.x, a.y));
  r.h[1] = __float22bfloat162_rn(make_float2(a.z, a.w));
  r.h[2] = __float22bfloat162_rn(make_float2(b.x, b.y));
  r.h[3] = __float22bfloat162_rn(make_float2(b.z, b.w));
  return r.v;
}

__device__ __forceinline__ void load_edge(const void* ei, int mode, int e, int E,
                                          int& s, int& d) {
  if (mode) {
    const long long* p = (const long long*)ei;
    s = (int)p[e];
    d = (int)p[(size_t)E + e];
  } else {
    const int* p = (const int*)ei;
    s = p[e];
    d = p[(size_t)E + e];
  }
}

// setup: W1/W2 transpose+bf16, edge dtype detect, deg zero — one launch
__global__ __launch_bounds__(256) void setup_k(const float* __restrict__ W1,
                                               const float* __restrict__ W2,
                                               const int* __restrict__ ei,
                                               unsigned short* __restrict__ Wt,
                                               unsigned short* __restrict__ Wt2,
                                               int* flag, int* deg, int N) {
  const int b = blockIdx.x, t = threadIdx.x;
  if (b < 128) {
    int idx = b * 256 + t;
    int j = idx & 63, k = idx >> 6;
    Wt[j * 512 + k] = bf16rne(W1[k * 64 + j]);
  } else if (b < 144) {
    int idx = (b - 128) * 256 + t;
    int j = idx & 63, k = idx >> 6;
    Wt2[j * 64 + k] = bf16rne(W2[k * 64 + j]);
  } else if (b == 144) {
    if (t == 0) {
      int allzero = 1;
      for (int k = 0; k < 64; ++k)
        if (ei[2 * k + 1] != 0) { allzero = 0; break; }
      *flag = allzero;
    }
  } else {
    int i = (b - 145) * 256 + t;
    if (i <= N) deg[i] = 0;
  }
}

// one-time edge compaction to int32 (incl. self-loops)
__global__ __launch_bounds__(256) void conv_k(const void* ei, const int* flag,
                                              int* __restrict__ src32,
                                              int* __restrict__ dst32,
                                              int E, int Et) {
  int e = blockIdx.x * 256 + threadIdx.x;
  if (e >= Et) return;
  int mode = *flag;
  int s, d;
  if (e < E) load_edge(ei, mode, e, E, s, d);
  else { s = e - E; d = s; }
  src32[e] = s;
  dst32[e] = d;
}

// XCD-partitioned histogram over compact dst32
__global__ __launch_bounds__(256) void histx_k(const int* __restrict__ dst32,
                                               int* deg, int Et, int N) {
  const int xcd = blockIdx.x & 7;
  const int grp = blockIdx.x >> 3;
  const int ngrp = gridDim.x >> 3;
  const int R = (N + 7) >> 3;
  const int lo = xcd * R;
  const int hi = min(lo + R, N);
  const int per = (Et + ngrp - 1) / ngrp;
  const int e0 = grp * per;
  const int e1 = min(e0 + per, Et);
  for (int e = e0 + (int)threadIdx.x; e < e1; e += 256) {
    int d = dst32[e];
    if (d >= lo && d < hi) atomicAdd(&deg[d], 1);
  }
}

__global__ __launch_bounds__(256) void psum_k(const int* __restrict__ deg,
                                              int* __restrict__ bsum, int N) {
  int i = blockIdx.x * 256 + threadIdx.x;
  int v = (i < N) ? deg[i] : 0;
#pragma unroll
  for (int o = 32; o; o >>= 1) v += __shfl_xor(v, o, 64);
  __shared__ int wsum[4];
  if ((threadIdx.x & 63) == 0) wsum[threadIdx.x >> 6] = v;
  __syncthreads();
  if (threadIdx.x == 0) bsum[blockIdx.x] = wsum[0] + wsum[1] + wsum[2] + wsum[3];
}

__global__ __launch_bounds__(1024) void bscan_k(const int* __restrict__ bsum,
                                                int* __restrict__ boff, int nb) {
  __shared__ int s[1024];
  int t = threadIdx.x;
  s[t] = (t < nb) ? bsum[t] : 0;
  __syncthreads();
  for (int off = 1; off < 1024; off <<= 1) {
    int v = (t >= off) ? s[t - off] : 0;
    __syncthreads();
    s[t] += v;
    __syncthreads();
  }
  if (t < nb) boff[t] = (t == 0) ? 0 : s[t - 1];
}

__global__ __launch_bounds__(256) void escan_k(const int* __restrict__ deg,
                                               const int* __restrict__ boff,
                                               int* __restrict__ start,
                                               int* __restrict__ cursor,
                                               int N, int Et) {
  int i = blockIdx.x * 256 + threadIdx.x;
  int t = threadIdx.x;
  int v = (i < N) ? deg[i] : 0;
  __shared__ int s[256];
  s[t] = v;
  __syncthreads();
  for (int off = 1; off < 256; off <<= 1) {
    int u = (t >= off) ? s[t - off] : 0;
    __syncthreads();
    s[t] += u;
    __syncthreads();
  }
  if (i < N) {
    int pos = boff[blockIdx.x] + s[t] - v;
    start[i] = pos;
    cursor[i] = pos;
  }
  if (i == 0) start[N] = Et;
}

// XCD-partitioned CSR fill over compact arrays
__global__ __launch_bounds__(256) void fillx_k(const int* __restrict__ src32,
                                               const int* __restrict__ dst32,
                                               int* cursor, int* __restrict__ csr,
                                               int Et, int N) {
  const int xcd = blockIdx.x & 7;
  const int grp = blockIdx.x >> 3;
  const int ngrp = gridDim.x >> 3;
  const int R = (N + 7) >> 3;
  const int lo = xcd * R;
  const int hi = min(lo + R, N);
  const int per = (Et + ngrp - 1) / ngrp;
  const int e0 = grp * per;
  const int e1 = min(e0 + per, Et);
  for (int e = e0 + (int)threadIdx.x; e < e1; e += 256) {
    int d = dst32[e];
    if (d >= lo && d < hi) {
      int pos = atomicAdd(&cursor[d], 1);
      csr[pos] = src32[e];
    }
  }
}

// xl1 = x@W1 via bf16 MFMA (no LDS) + fused attn1 dots
__global__ __launch_bounds__(256) void gemm1_mfma(const float* __restrict__ x,
                                                  const unsigned short* __restrict__ Wt,
                                                  const float* __restrict__ attS1,
                                                  const float* __restrict__ attD1,
                                                  unsigned short* __restrict__ xlh,
                                                  float* __restrict__ a_src,
                                                  float* __restrict__ a_dst, int N) {
  const int t = threadIdx.x;
  const int w = t >> 6, lane = t & 63;
  const int row0 = blockIdx.x * 64;
  int arow = row0 + w * 16 + (lane & 15);
  if (arow > N - 1) arow = N - 1;
  const int koff = (lane >> 4) * 8;
  const int bcol = lane & 15;
  const int bk = (lane >> 4) * 8;
  const float* xrow = x + (size_t)arow * 512 + koff;

  f32x4 acc[4] = {f32x4{0.f, 0.f, 0.f, 0.f}, f32x4{0.f, 0.f, 0.f, 0.f},
                  f32x4{0.f, 0.f, 0.f, 0.f}, f32x4{0.f, 0.f, 0.f, 0.f}};
#pragma unroll 4
  for (int ks = 0; ks < 16; ++ks) {
    const float4* g = (const float4*)(xrow + ks * 32);
    bf16x8 afrag = pack8(g[0], g[1]);
#pragma unroll
    for (int nt = 0; nt < 4; ++nt) {
      bf16x8 bfrag = *(const bf16x8*)(Wt + (nt * 16 + bcol) * 512 + ks * 32 + bk);
      acc[nt] = __builtin_amdgcn_mfma_f32_16x16x32_bf16(afrag, bfrag, acc[nt], 0, 0, 0);
    }
  }
  const int orow = row0 + w * 16 + (lane >> 4) * 4;
#pragma unroll
  for (int nt = 0; nt < 4; ++nt)
#pragma unroll
    for (int r = 0; r < 4; ++r) {
      int rr = orow + r;
      if (rr < N) xlh[(size_t)rr * 64 + nt * 16 + bcol] = bf16rne(acc[nt][r]);
    }
  float aS[4], aD[4];
#pragma unroll
  for (int nt = 0; nt < 4; ++nt) {
    aS[nt] = attS1[nt * 16 + bcol];
    aD[nt] = attD1[nt * 16 + bcol];
  }
#pragma unroll
  for (int r = 0; r < 4; ++r) {
    int rr = orow + r;
#pragma unroll
    for (int nt = 0; nt < 4; ++nt) {
      float vS = acc[nt][r] * aS[nt];
      float vD = acc[nt][r] * aD[nt];
      vS += __shfl_xor(vS, 1, 64);
      vD += __shfl_xor(vD, 1, 64);
      vS += __shfl_xor(vS, 2, 64);
      vD += __shfl_xor(vD, 2, 64);
      vS += __shfl_xor(vS, 4, 64);
      vD += __shfl_xor(vD, 4, 64);
      if ((bcol & 7) == 0 && rr < N) {
        int head = nt * 2 + (bcol >> 3);
        a_src[rr * 8 + head] = vS;
        a_dst[rr * 8 + head] = vD;
      }
    }
  }
}

// layer-1 gather: lane=(edge-slot es, col-group cg); no max pass
__global__ __launch_bounds__(256) void gather1(const int* __restrict__ start,
                                               const int* __restrict__ csr,
                                               const float* __restrict__ asrc,
                                               const float* __restrict__ adst,
                                               const unsigned short* __restrict__ xlh,
                                               const float* __restrict__ b1,
                                               unsigned short* __restrict__ hbufh,
                                               int N) {
  int g = blockIdx.x * 256 + threadIdx.x;
  int n = g >> 6;
  if (n >= N) return;
  const int lane = threadIdx.x & 63;
  const int es = lane >> 3, cg = lane & 7;
  const int s0 = start[n];
  const int deg = start[n + 1] - s0;
  const float adn = adst[n * 8 + cg];

  float acc[8] = {0.f, 0.f, 0.f, 0.f, 0.f, 0.f, 0.f, 0.f};
  float dsum = 0.f;

  for (int base = 0; base < deg; base += 64) {
    int rem = deg - base;
    if (rem > 64) rem = 64;
    int sreg = (lane < rem) ? csr[s0 + base + lane] : 0;
    for (int jb = 0; jb * 8 < rem; ++jb) {
      const int idx = jb * 8 + es;
      const int s = __shfl(sreg, idx, 64);
      const bool valid = idx < rem;
      float ev = leaky(asrc[s * 8 + cg] + adn);
      float w = valid ? __expf(ev) : 0.f;
      dsum += w;
      const uint4 row = *(const uint4*)(xlh + (size_t)s * 64 + cg * 8);
      acc[0] = fmaf(w, __uint_as_float(row.x << 16), acc[0]);
      acc[1] = fmaf(w, __uint_as_float(row.x & 0xffff0000u), acc[1]);
      acc[2] = fmaf(w, __uint_as_float(row.y << 16), acc[2]);
      acc[3] = fmaf(w, __uint_as_float(row.y & 0xffff0000u), acc[3]);
      acc[4] = fmaf(w, __uint_as_float(row.z << 16), acc[4]);
      acc[5] = fmaf(w, __uint_as_float(row.z & 0xffff0000u), acc[5]);
      acc[6] = fmaf(w, __uint_as_float(row.w << 16), acc[6]);
      acc[7] = fmaf(w, __uint_as_float(row.w & 0xffff0000u), acc[7]);
    }
  }
#pragma unroll
  for (int o = 8; o < 64; o <<= 1) {
    dsum += __shfl_xor(dsum, o, 64);
#pragma unroll
    for (int c = 0; c < 8; ++c) acc[c] += __shfl_xor(acc[c], o, 64);
  }
  if (es == 0) {
    const float inv = 1.f / fmaxf(dsum, 1e-16f);
    float v[8];
#pragma unroll
    for (int c = 0; c < 8; ++c) {
      float t = acc[c] * inv + b1[cg * 8 + c];
      v[c] = t > 0.f ? t : __expf(t) - 1.f;
    }
    uint4 od;
    od.x = pack2(v[0], v[1]);
    od.y = pack2(v[2], v[3]);
    od.z = pack2(v[4], v[5]);
    od.w = pack2(v[6], v[7]);
    *(uint4*)(hbufh + (size_t)n * 64 + cg * 8) = od;
  }
}

// xl2 = h@W2 via bf16 MFMA + fused attn2
__global__ __launch_bounds__(256) void gemm2_mfma(const unsigned short* __restrict__ hbufh,
                                                  const unsigned short* __restrict__ Wt2,
                                                  const float* __restrict__ attS2,
                                                  const float* __restrict__ attD2,
                                                  unsigned short* __restrict__ xl2h,
                                                  float* __restrict__ a2s,
                                                  float* __restrict__ a2d, int N) {
  const int t = threadIdx.x;
  const int w = t >> 6, lane = t & 63;
  const int row0 = blockIdx.x * 64;
  const int bcol = lane & 15;
  const int bk = (lane >> 4) * 8;
  int arow = row0 + w * 16 + (lane & 15);
  if (arow > N - 1) arow = N - 1;
  f32x4 acc[4] = {f32x4{0.f, 0.f, 0.f, 0.f}, f32x4{0.f, 0.f, 0.f, 0.f},
                  f32x4{0.f, 0.f, 0.f, 0.f}, f32x4{0.f, 0.f, 0.f, 0.f}};
#pragma unroll
  for (int ks = 0; ks < 2; ++ks) {
    bf16x8 afrag = *(const bf16x8*)(hbufh + (size_t)arow * 64 + ks * 32 + bk);
#pragma unroll
    for (int nt = 0; nt < 4; ++nt) {
      bf16x8 bfrag = *(const bf16x8*)(Wt2 + (nt * 16 + bcol) * 64 + ks * 32 + bk);
      acc[nt] = __builtin_amdgcn_mfma_f32_16x16x32_bf16(afrag, bfrag, acc[nt], 0, 0, 0);
    }
  }
  const int orow = row0 + w * 16 + (lane >> 4) * 4;
#pragma unroll
  for (int nt = 0; nt < 4; ++nt)
#pragma unroll
    for (int r = 0; r < 4; ++r) {
      int rr = orow + r;
      if (rr < N) xl2h[(size_t)rr * 64 + nt * 16 + bcol] = bf16rne(acc[nt][r]);
    }
  float aS[4], aD[4];
#pragma unroll
  for (int nt = 0; nt < 4; ++nt) {
    aS[nt] = attS2[nt * 16 + bcol];
    aD[nt] = attD2[nt * 16 + bcol];
  }
#pragma unroll
  for (int r = 0; r < 4; ++r) {
    int rr = orow + r;
    float vS = 0.f, vD = 0.f;
#pragma unroll
    for (int nt = 0; nt < 4; ++nt) {
      vS += acc[nt][r] * aS[nt];
      vD += acc[nt][r] * aD[nt];
    }
    vS += __shfl_xor(vS, 1, 64);
    vD += __shfl_xor(vD, 1, 64);
    vS += __shfl_xor(vS, 2, 64);
    vD += __shfl_xor(vD, 2, 64);
    vS += __shfl_xor(vS, 4, 64);
    vD += __shfl_xor(vD, 4, 64);
    vS += __shfl_xor(vS, 8, 64);
    vD += __shfl_xor(vD, 8, 64);
    if (bcol == 0 && rr < N) {
      a2s[rr] = vS;
      a2d[rr] = vD;
    }
  }
}

// layer-2 gather + bias + log_softmax, (es,cg) structure
__global__ __launch_bounds__(256) void gather2(const int* __restrict__ start,
                                               const int* __restrict__ csr,
                                               const float* __restrict__ a2s,
                                               const float* __restrict__ a2d,
                                               const unsigned short* __restrict__ xl2h,
                                               const float* __restrict__ b2,
                                               float* __restrict__ out, int N) {
  int g = blockIdx.x * 256 + threadIdx.x;
  int n = g >> 6;
  if (n >= N) return;
  const int lane = threadIdx.x & 63;
  const int es = lane >> 3, cg = lane & 7;
  const int s0 = start[n];
  const int deg = start[n + 1] - s0;
  const float adn = a2d[n];

  float acc[8] = {0.f, 0.f, 0.f, 0.f, 0.f, 0.f, 0.f, 0.f};
  float dsum = 0.f;

  for (int base = 0; base < deg; base += 64) {
    int rem = deg - base;
    if (rem > 64) rem = 64;
    int sreg = (lane < rem) ? csr[s0 + base + lane] : 0;
    for (int jb = 0; jb * 8 < rem; ++jb) {
      const int idx = jb * 8 + es;
      const int s = __shfl(sreg, idx, 64);
      const bool valid = idx < rem;
      float ev = leaky(a2s[s] + adn);
      float w = valid ? __expf(ev) : 0.f;
      dsum += w;
      const uint4 row = *(const uint4*)(xl2h + (size_t)s * 64 + cg * 8);
      acc[0] = fmaf(w, __uint_as_float(row.x << 16), acc[0]);
      acc[1] = fmaf(w, __uint_as_float(row.x & 0xffff0000u), acc[1]);
      acc[2] = fmaf(w, __uint_as_float(row.y << 16), acc[2]);
      acc[3] = fmaf(w, __uint_as_float(row.y & 0xffff0000u), acc[3]);
      acc[4] = fmaf(w, __uint_as_float(row.z << 16), acc[4]);
      acc[5] = fmaf(w, __uint_as_float(row.z & 0xffff0000u), acc[5]);
      acc[6] = fmaf(w, __uint_as_float(row.w << 16), acc[6]);
      acc[7] = fmaf(w, __uint_as_float(row.w & 0xffff0000u), acc[7]);
    }
  }
#pragma unroll
  for (int o = 8; o < 64; o <<= 1) {
    dsum += __shfl_xor(dsum, o, 64);
#pragma unroll
    for (int c = 0; c < 8; ++c) acc[c] += __shfl_xor(acc[c], o, 64);
  }
  const float inv = 1.f / fmaxf(dsum, 1e-16f);
  float v[8];
  float mm = -INFINITY;
#pragma unroll
  for (int c = 0; c < 8; ++c) {
    v[c] = acc[c] * inv + b2[cg * 8 + c];
    mm = fmaxf(mm, v[c]);
  }
  mm = fmaxf(mm, __shfl_xor(mm, 1, 64));
  mm = fmaxf(mm, __shfl_xor(mm, 2, 64));
  mm = fmaxf(mm, __shfl_xor(mm, 4, 64));
  float ss = 0.f;
#pragma unroll
  for (int c = 0; c < 8; ++c) ss += __expf(v[c] - mm);
  ss += __shfl_xor(ss, 1, 64);
  ss += __shfl_xor(ss, 2, 64);
  ss += __shfl_xor(ss, 4, 64);
  const float lg = mm + logf(ss);
  if (es == 0) {
    float4 o0 = {v[0] - lg, v[1] - lg, v[2] - lg, v[3] - lg};
    float4 o1 = {v[4] - lg, v[5] - lg, v[6] - lg, v[7] - lg};
    float4* op = (float4*)(out + (size_t)n * 64 + cg * 8);
    op[0] = o0;
    op[1] = o1;
  }
}

extern "C" void kernel_launch(void* const* d_in, const int* in_sizes, int n_in,
                              void* d_out, int out_size, void* d_ws, size_t ws_size,
                              hipStream_t stream) {
  const float* x = (const float*)d_in[0];
  const void* ei = d_in[1];
  const float* W1 = (const float*)d_in[2];
  const float* att_src1 = (const float*)d_in[3];
  const float* att_dst1 = (const float*)d_in[4];
  const float* b1 = (const float*)d_in[5];
  const float* W2 = (const float*)d_in[6];
  const float* att_src2 = (const float*)d_in[7];
  const float* att_dst2 = (const float*)d_in[8];
  const float* b2 = (const float*)d_in[9];
  float* out = (float*)d_out;

  const int N = in_sizes[0] / 512;
  const int E = in_sizes[1] / 2;
  const int Et = E + N;
  const int nb = (N + 255) / 256;
  const int nz = (N + 1 + 255) / 256;

  float* ws = (float*)d_ws;
  size_t o = 0;
  unsigned short* xlh = (unsigned short*)(ws + o); o += (size_t)N * 32;
  unsigned short* hbufh = (unsigned short*)(ws + o); o += (size_t)N * 32;
  unsigned short* xl2h = (unsigned short*)(ws + o); o += (size_t)N * 32;
  unsigned short* Wt = (unsigned short*)(ws + o); o += 16384;
  unsigned short* Wt2 = (unsigned short*)(ws + o); o += 2048;
  float* asrc1 = ws + o; o += (size_t)N * 8;
  float* adst1 = ws + o; o += (size_t)N * 8;
  float* a2s = ws + o; o += (size_t)N;
  float* a2d = ws + o; o += (size_t)N;
  int* deg = (int*)(ws + o); o += (size_t)N + 1;
  int* start = (int*)(ws + o); o += (size_t)N + 1;
  int* cursor = (int*)(ws + o); o += (size_t)N + 1;
  int* csr = (int*)(ws + o); o += (size_t)Et;
  int* src32 = (int*)(ws + o); o += (size_t)Et;
  int* dst32 = (int*)(ws + o); o += (size_t)Et;
  int* flag = (int*)(ws + o); o += 1;
  int* bsum = (int*)(ws + o); o += (size_t)nb;
  int* boff = (int*)(ws + o); o += (size_t)nb;

  setup_k<<<145 + nz, 256, 0, stream>>>(W1, W2, (const int*)ei, Wt, Wt2, flag, deg, N);
  conv_k<<<(Et + 255) / 256, 256, 0, stream>>>(ei, flag, src32, dst32, E, Et);
  // CSR build (XCD-partitioned hist/fill over compact int32)
  histx_k<<<2048, 256, 0, stream>>>(dst32, deg, Et, N);
  psum_k<<<nb, 256, 0, stream>>>(deg, bsum, N);
  bscan_k<<<1, 1024, 0, stream>>>(bsum, boff, nb);
  escan_k<<<nb, 256, 0, stream>>>(deg, boff, start, cursor, N, Et);
  fillx_k<<<2048, 256, 0, stream>>>(src32, dst32, cursor, csr, Et, N);
  // layer 1
  gemm1_mfma<<<(N + 63) / 64, 256, 0, stream>>>(x, Wt, att_src1, att_dst1, xlh,
                                                asrc1, adst1, N);
  gather1<<<(N * 64 + 255) / 256, 256, 0, stream>>>(start, csr, asrc1, adst1, xlh,
                                                    b1, hbufh, N);
  // layer 2
  gemm2_mfma<<<(N + 63) / 64, 256, 0, stream>>>(hbufh, Wt2, att_src2, att_dst2,
                                                xl2h, a2s, a2d, N);
  gather2<<<(N * 64 + 255) / 256, 256, 0, stream>>>(start, csr, a2s, a2d, xl2h,
                                                    b2, out, N);
}